// Round 8
// baseline (341.277 us; speedup 1.0000x reference)
//
#include <hip/hip_runtime.h>

typedef unsigned short u16;
typedef __attribute__((ext_vector_type(4))) float f32x4;
typedef __attribute__((ext_vector_type(8))) short bf16x8;

#define MAXB 512      // max coarse buckets one scan block supports
#define BUK  256      // dst rows per coarse bucket
#define EMAX 4096     // max edges per bucket (mean 3072, ~18 sigma headroom)

__device__ __forceinline__ float bf2f(u16 u) {
    union { unsigned int i; float f; } v; v.i = ((unsigned int)u) << 16; return v.f;
}
__device__ __forceinline__ u16 f2bf(float f) {
    union { float f; unsigned int i; } v; v.f = f;
    unsigned int r = v.i + 0x7fffu + ((v.i >> 16) & 1u);
    return (u16)(r >> 16);
}
__device__ __forceinline__ void gload16(const void* g, void* l) {
    __builtin_amdgcn_global_load_lds(
        (const __attribute__((address_space(1))) unsigned int*)g,
        (__attribute__((address_space(3))) unsigned int*)l, 16, 0, 0);
}

// 256 thr = 4 waves, 128x128 C tile, wave = 64x64 (4x4 of 16x16x32 bf16 MFMA)
#define MFMA_VARS \
    const int tid = threadIdx.x, w = tid >> 6, l = tid & 63; \
    const int wr = (w >> 1) * 64, wc = (w & 1) * 64; \
    const int quad = l >> 4, lan = l & 15; (void)tid;

#define ACC_INIT(A) \
    _Pragma("unroll") for (int i = 0; i < 4; i++) \
    _Pragma("unroll") for (int j = 0; j < 4; j++) A[i][j] = (f32x4){0.f,0.f,0.f,0.f};

// stage 32KB A-tile + 32KB W-tile (128 rows x 128 bf16 each) via async DMA
#define STAGE_AW(Aptr, sA, Wptr, sW) \
    _Pragma("unroll") for (int it = 0; it < 8; it++) { \
        int o = ((it * 4 + w) * 64 + l) * 16; \
        int row = o >> 8, cb = o & 255; \
        gload16((Aptr) + (size_t)row * (sA) + (cb >> 1), (char*)As + o); \
        gload16((Wptr) + (size_t)row * (sW) + (cb >> 1), (char*)Ws + o); \
    }

#define STAGE_W(Wptr, sW) \
    _Pragma("unroll") for (int it = 0; it < 8; it++) { \
        int o = ((it * 4 + w) * 64 + l) * 16; \
        int row = o >> 8, cb = o & 255; \
        gload16((Wptr) + (size_t)row * (sW) + (cb >> 1), (char*)Ws + o); \
    }

#define COMPUTE(A) \
    _Pragma("unroll") for (int kk = 0; kk < 4; kk++) { \
        bf16x8 af[4], bfr[4]; \
        _Pragma("unroll") for (int i = 0; i < 4; i++) \
            af[i] = *(const bf16x8*)&As[(wr + i*16 + lan)*128 + kk*32 + quad*8]; \
        _Pragma("unroll") for (int j = 0; j < 4; j++) \
            bfr[j] = *(const bf16x8*)&Ws[(wc + j*16 + lan)*128 + kk*32 + quad*8]; \
        _Pragma("unroll") for (int i = 0; i < 4; i++) \
        _Pragma("unroll") for (int j = 0; j < 4; j++) \
            A[i][j] = __builtin_amdgcn_mfma_f32_16x16x32_bf16(af[i], bfr[j], A[i][j], 0,0,0); \
    }

// ---------------------------------------------------------------------------
// msgln: x = S @ Wrel^T + fb @ Wself^T + bm; h = relu(LN(x)*g + b) + fb.
// LN stats computed in-register (shfl within 16-lane groups) + 2KB LDS
// half-exchange. Residual fb read from LDS As (still staged from chunk 2).
// Writes h in-place over fb (bf16).
// ---------------------------------------------------------------------------
__global__ __launch_bounds__(256) void msgln_k(
    const u16* __restrict__ S, u16* __restrict__ fb,
    const u16* __restrict__ wUrel, const u16* __restrict__ wUself,
    const u16* __restrict__ wIrel, const u16* __restrict__ wIself,
    const float* __restrict__ bmU, const float* __restrict__ bmI,
    const float* __restrict__ gU, const float* __restrict__ bU,
    const float* __restrict__ gI, const float* __restrict__ bI,
    int NUp)
{
    __shared__ __align__(16) u16 As[128 * 128];
    __shared__ __align__(16) u16 Ws[128 * 128];
    __shared__ float ps[128][2][2];
    MFMA_VARS
    const int m0 = blockIdx.x * 128;
    const bool isU = m0 < NUp;
    const u16* W0 = isU ? wUrel : wIrel;
    const u16* W1 = isU ? wUself : wIself;
    const float* bm = isU ? bmU : bmI;
    const float* g  = isU ? gU : gI;
    const float* b  = isU ? bU : bI;

    f32x4 acc[4][4];
    ACC_INIT(acc)

    STAGE_AW(S + (size_t)m0 * 128, 128, W0, 128)
    __syncthreads();
    COMPUTE(acc)
    __syncthreads();
    STAGE_AW(fb + (size_t)m0 * 128, 128, W1, 128)
    __syncthreads();
    COMPUTE(acc)

    const int half = wc >> 6;
    float bm4[4], g4[4], b4[4];
#pragma unroll
    for (int j = 0; j < 4; j++) {
        int col = wc + j * 16 + lan;
        bm4[j] = bm[col]; g4[j] = g[col]; b4[j] = b[col];
    }
    // per-row partial stats over this wave's 64 cols
#pragma unroll
    for (int i = 0; i < 4; i++) {
#pragma unroll
        for (int r = 0; r < 4; r++) {
            float s = 0.f, q = 0.f;
#pragma unroll
            for (int j = 0; j < 4; j++) {
                float v = acc[i][j][r] + bm4[j];
                s += v; q += v * v;
            }
#pragma unroll
            for (int o = 1; o < 16; o <<= 1) {
                s += __shfl_xor(s, o, 64);
                q += __shfl_xor(q, o, 64);
            }
            if (lan == 0) {
                int rl = wr + i * 16 + quad * 4 + r;
                ps[rl][half][0] = s;
                ps[rl][half][1] = q;
            }
        }
    }
    __syncthreads();
#pragma unroll
    for (int i = 0; i < 4; i++) {
#pragma unroll
        for (int r = 0; r < 4; r++) {
            int rl = wr + i * 16 + quad * 4 + r;
            float sum = ps[rl][0][0] + ps[rl][1][0];
            float sq  = ps[rl][0][1] + ps[rl][1][1];
            float mean = sum * 0.0078125f;
            float var  = sq * 0.0078125f - mean * mean;
            float inv  = rsqrtf(var + 1e-5f);
#pragma unroll
            for (int j = 0; j < 4; j++) {
                int col = wc + j * 16 + lan;
                float v = acc[i][j][r] + bm4[j];
                float y = fmaxf(fmaf((v - mean) * inv, g4[j], b4[j]), 0.f)
                          + bf2f(As[rl * 128 + col]);
                fb[(size_t)(m0 + rl) * 128 + col] = f2bf(y);
            }
        }
    }
}

// ---------------------------------------------------------------------------
// Fused FFN: out = relu(h @ W1T^T + b1) @ W2T^T + b2.
// Phase 1: hid[128][256] in regs (two W1 col-halves), then into 64KB LDS
// (bf16, A-operand layout). Phase 2: K=256 MFMA, W2T streamed from global
// (64KB, L2-resident). fp32 out with pad-skip row remap.
// ---------------------------------------------------------------------------
__global__ __launch_bounds__(256) void ffn_k(
    const u16* __restrict__ h, const u16* __restrict__ W1T,
    const float* __restrict__ b1, const u16* __restrict__ W2T,
    const float* __restrict__ b2, float* __restrict__ out,
    int NU, int NUp, int NI)
{
    __shared__ __align__(16) u16 lds[2 * 128 * 128];
    u16* As = lds;
    u16* Ws = lds + 16384;
    MFMA_VARS
    const int m0 = blockIdx.x * 128;

    f32x4 acc1[4][4], acc2[4][4];
    ACC_INIT(acc1)
    ACC_INIT(acc2)

    STAGE_AW(h + (size_t)m0 * 128, 128, W1T, 128)
    __syncthreads();
    COMPUTE(acc1)
    __syncthreads();
    STAGE_W(W1T + (size_t)128 * 128, 128)
    __syncthreads();
    COMPUTE(acc2)
    __syncthreads();   // all waves done reading As/Ws

    // hid -> LDS as [row][256] bf16 (relu + b1)
    float b1a[4], b1b[4];
#pragma unroll
    for (int j = 0; j < 4; j++) {
        b1a[j] = b1[wc + j * 16 + lan];
        b1b[j] = b1[128 + wc + j * 16 + lan];
    }
    u16* H = lds;
#pragma unroll
    for (int i = 0; i < 4; i++) {
#pragma unroll
        for (int r = 0; r < 4; r++) {
            int rl = wr + i * 16 + quad * 4 + r;
#pragma unroll
            for (int j = 0; j < 4; j++) {
                int col = wc + j * 16 + lan;
                H[rl * 256 + col]       = f2bf(fmaxf(acc1[i][j][r] + b1a[j], 0.f));
                H[rl * 256 + 128 + col] = f2bf(fmaxf(acc2[i][j][r] + b1b[j], 0.f));
            }
        }
    }
    __syncthreads();

    // phase 2: out-tile = H @ W2T^T  (K = 256)
    f32x4 acc3[4][4];
    ACC_INIT(acc3)
#pragma unroll
    for (int kk = 0; kk < 8; kk++) {
        bf16x8 af[4], bfr[4];
#pragma unroll
        for (int i = 0; i < 4; i++)
            af[i] = *(const bf16x8*)&H[(wr + i * 16 + lan) * 256 + kk * 32 + quad * 8];
#pragma unroll
        for (int j = 0; j < 4; j++)
            bfr[j] = *(const bf16x8*)&W2T[(size_t)(wc + j * 16 + lan) * 256 + kk * 32 + quad * 8];
#pragma unroll
        for (int i = 0; i < 4; i++)
#pragma unroll
            for (int j = 0; j < 4; j++)
                acc3[i][j] = __builtin_amdgcn_mfma_f32_16x16x32_bf16(af[i], bfr[j], acc3[i][j], 0, 0, 0);
    }

#pragma unroll
    for (int j = 0; j < 4; j++) {
        int col = wc + j * 16 + lan;
        float bb = b2[col];
#pragma unroll
        for (int i = 0; i < 4; i++) {
            int row0 = m0 + wr + i * 16 + quad * 4;
#pragma unroll
            for (int r = 0; r < 4; r++) {
                int gr = row0 + r, orow;
                if (gr < NUp) { if (gr >= NU) continue; orow = gr; }
                else { int ir = gr - NUp; if (ir >= NI) continue; orow = NU + ir; }
                out[(size_t)orow * 128 + col] = acc3[i][j][r] + bb;
            }
        }
    }
}

// ---------------------------------------------------------------------------
// prep: feature casts (user-first padded layout) + 6 weight transposes +
// cnt zeroing + pad-row zeroing of S and fb.
// ---------------------------------------------------------------------------
__global__ __launch_bounds__(256) void prep_k(
    const float* __restrict__ fu, const float* __restrict__ fi,
    u16* __restrict__ fb, u16* __restrict__ S,
    int nu4, int ni4, int NU, int NUp, int NI, int NIp,
    const float* __restrict__ w0, const float* __restrict__ w1,
    const float* __restrict__ w2, const float* __restrict__ w3,
    const float* __restrict__ w4, const float* __restrict__ w5,
    u16* __restrict__ o0, u16* __restrict__ o1, u16* __restrict__ o2,
    u16* __restrict__ o3, u16* __restrict__ o4, u16* __restrict__ o5,
    int* __restrict__ cnt, int NBUK)
{
    int t = blockIdx.x * 256 + threadIdx.x;
    int nc = nu4 + ni4;
    if (t < nc) {
        const float* X; u16* Y; int idx;
        if (t < nu4) { X = fu; Y = fb; idx = t; }
        else { X = fi; Y = fb + (size_t)NUp * 128; idx = t - nu4; }
        float4 v = ((const float4*)X)[idx];
        ((ushort4*)Y)[idx] = make_ushort4(f2bf(v.x), f2bf(v.y), f2bf(v.z), f2bf(v.w));
        return;
    }
    int u = t - nc;
    if (u < 131072) {
        const float* W; u16* O; int K, N, idx;
        if (u < 65536) {
            int s = u >> 14; idx = u & 16383; K = 128; N = 128;
            W = s == 0 ? w0 : s == 1 ? w1 : s == 2 ? w2 : w3;
            O = s == 0 ? o0 : s == 1 ? o1 : s == 2 ? o2 : o3;
        } else {
            int v2 = u - 65536; int s = v2 >> 15; idx = v2 & 32767;
            if (s == 0) { W = w4; O = o4; K = 128; N = 256; }
            else        { W = w5; O = o5; K = 256; N = 128; }
        }
        int k = idx / N, n = idx % N;
        O[n * K + k] = f2bf(W[idx]);
        return;
    }
    int u2 = u - 131072;
    int padrows = (NUp - NU) + (NIp - NI);
    int padw = padrows * 32;           // ushort4 per array
    if (u2 < 2 * padw) {
        int arr = u2 / padw, k = u2 % padw;
        int prow = k >> 5, c4 = k & 31;
        int row = (prow < NUp - NU) ? (NU + prow) : (NUp + NI + (prow - (NUp - NU)));
        u16* B = arr ? fb : S;
        ((ushort4*)B)[(size_t)row * 32 + c4] = make_ushort4(0, 0, 0, 0);
        return;
    }
    int c = u2 - 2 * padw;
    if (c <= NBUK) cnt[c] = 0;
}

// ---------------------------------------------------------------------------
// CSR build: coarse histogram -> scan -> partition -> per-bucket LDS sort.
// CSR row space item-first: [0,NI)=item dst, [NI,NR)=user dst.
// ---------------------------------------------------------------------------
__global__ __launch_bounds__(256) void chist_k(
    const int* __restrict__ dst0, const int* __restrict__ dst1,
    int* __restrict__ cnt, int E, int NI, int NBUK)
{
    __shared__ int lh[MAXB];
    int t = threadIdx.x;
    for (int i = t; i < MAXB; i += 256) lh[i] = 0;
    __syncthreads();
    for (long long e = (long long)blockIdx.x * 256 + t; e < 2LL * E;
         e += (long long)gridDim.x * 256) {
        int row = (e < E) ? dst0[e] : NI + dst1[e - E];
        atomicAdd(&lh[row >> 8], 1);
    }
    __syncthreads();
    for (int i = t; i < NBUK; i += 256)
        if (lh[i]) atomicAdd(&cnt[i], lh[i]);
}

__global__ __launch_bounds__(512) void cscan_k(
    const int* __restrict__ cnt, int* __restrict__ crp, int* __restrict__ chead,
    int* __restrict__ rowptr, int NBUK, int NR)
{
    __shared__ int s[512];
    int t = threadIdx.x;
    int carry = 0;
    for (int base = 0; base < NBUK; base += 512) {
        int i = base + t;
        int v = (i < NBUK) ? cnt[i] : 0;
        s[t] = v;
        __syncthreads();
        for (int off = 1; off < 512; off <<= 1) {
            int x = (t >= off) ? s[t - off] : 0;
            __syncthreads();
            s[t] += x;
            __syncthreads();
        }
        int excl = s[t] - v + carry;
        if (i < NBUK) { crp[i] = excl; chead[i] = excl; }
        carry += s[511];
        __syncthreads();
    }
    if (t == 0) { crp[NBUK] = carry; rowptr[NR] = carry; }
}

__global__ __launch_bounds__(256) void cpart_k(
    const int* __restrict__ src0, const int* __restrict__ dst0,
    const int* __restrict__ src1, const int* __restrict__ dst1,
    int* __restrict__ chead, unsigned int* __restrict__ ebuf,
    int E, int NI, int NBUK)
{
    __shared__ int lh[MAXB], lb[MAXB], lo[MAXB];
    int t = threadIdx.x;
    long long total = 2LL * E;
    long long per = (total + gridDim.x - 1) / gridDim.x;
    long long r0 = (long long)blockIdx.x * per;
    long long r1 = r0 + per; if (r1 > total) r1 = total;

    for (int i = t; i < MAXB; i += 256) { lh[i] = 0; lo[i] = 0; }
    __syncthreads();
    for (long long e = r0 + t; e < r1; e += 256) {
        int row = (e < E) ? dst0[e] : NI + dst1[e - E];
        atomicAdd(&lh[row >> 8], 1);
    }
    __syncthreads();
    for (int i = t; i < NBUK; i += 256)
        if (lh[i]) lb[i] = atomicAdd(&chead[i], lh[i]);
    __syncthreads();
    for (long long e = r0 + t; e < r1; e += 256) {
        int row, src;
        if (e < E) { row = dst0[e]; src = src0[e]; }
        else       { row = NI + dst1[e - E]; src = src1[e - E]; }
        int bin = row >> 8;
        int off = atomicAdd(&lo[bin], 1);
        ebuf[lb[bin] + off] = ((unsigned int)(row & 255) << 16) | (unsigned int)src;
    }
}

__global__ __launch_bounds__(256) void fsort_k(
    const int* __restrict__ crp, const unsigned int* __restrict__ ebuf,
    int* __restrict__ rowptr, u16* __restrict__ eidx, int NR)
{
    __shared__ unsigned int ep[EMAX];
    __shared__ u16 ss[EMAX];
    __shared__ int h[BUK], hd[BUK];
    int b = blockIdx.x, t = threadIdx.x;
    int base = crp[b];
    int n = crp[b + 1] - base;
    if (n > EMAX) n = EMAX;

    for (int i = t; i < n; i += 256) ep[i] = ebuf[base + i];
    if (t < BUK) h[t] = 0;
    __syncthreads();
    for (int i = t; i < n; i += 256) atomicAdd(&h[ep[i] >> 16], 1);
    __syncthreads();
    int v = (t < BUK) ? h[t] : 0;
    for (int off = 1; off < 256; off <<= 1) {
        int x = (t >= off) ? h[t - off] : 0;
        __syncthreads();
        if (t < BUK) h[t] += x;
        __syncthreads();
    }
    int excl = (t < BUK) ? (h[t] - v) : 0;
    if (t < BUK) {
        int absrow = b * BUK + t;
        if (absrow < NR) rowptr[absrow] = base + excl;
        hd[t] = excl;
    }
    __syncthreads();
    for (int i = t; i < n; i += 256) {
        unsigned int p = ep[i];
        int pos = atomicAdd(&hd[p >> 16], 1);
        ss[pos] = (u16)(p & 0xffffu);
    }
    __syncthreads();
    for (int i = t; i < n; i += 256) eidx[base + i] = ss[i];
}

// ---------------------------------------------------------------------------
// Gather: wave per csr row, 16 edges in flight (4 clamped uint4 loads,
// predicated accumulate), fp32 acc, shfl-reduce, bf16 out (padded layout).
// ---------------------------------------------------------------------------
__global__ __launch_bounds__(256) void gather_k(
    const int* __restrict__ rowptr, const u16* __restrict__ eidx,
    const u16* __restrict__ fb, u16* __restrict__ S,
    int NI, int NR, int NUp)
{
    int row = blockIdx.x * 4 + (threadIdx.x >> 6);
    int l = threadIdx.x & 63;
    if (row >= NR) return;
    const u16* F = (row < NI) ? fb : fb + (size_t)NUp * 128;
    int srow = (row < NI) ? (NUp + row) : (row - NI);
    int start = rowptr[row], end = rowptr[row + 1];
    int sub = l >> 4, li = l & 15;

    float a[8];
#pragma unroll
    for (int k = 0; k < 8; k++) a[k] = 0.f;

    for (int j = start; j < end; j += 16) {
        int idx[4]; uint4 v[4];
#pragma unroll
        for (int u = 0; u < 4; u++) {
            int je = j + u * 4 + sub;
            int c = je < end ? je : end - 1;
            idx[u] = eidx[c];
        }
#pragma unroll
        for (int u = 0; u < 4; u++)
            v[u] = *(const uint4*)(F + (size_t)idx[u] * 128 + li * 8);
#pragma unroll
        for (int u = 0; u < 4; u++) {
            if (j + u * 4 + sub < end) {
                unsigned int ww[4] = {v[u].x, v[u].y, v[u].z, v[u].w};
#pragma unroll
                for (int p = 0; p < 4; p++) {
                    a[2*p]   += bf2f((u16)(ww[p] & 0xffffu));
                    a[2*p+1] += bf2f((u16)(ww[p] >> 16));
                }
            }
        }
    }
#pragma unroll
    for (int k = 0; k < 8; k++) {
        a[k] += __shfl_xor(a[k], 16, 64);
        a[k] += __shfl_xor(a[k], 32, 64);
    }
    if (sub == 0) {
        uint4 o;
        o.x = ((unsigned int)f2bf(a[1]) << 16) | f2bf(a[0]);
        o.y = ((unsigned int)f2bf(a[3]) << 16) | f2bf(a[2]);
        o.z = ((unsigned int)f2bf(a[5]) << 16) | f2bf(a[4]);
        o.w = ((unsigned int)f2bf(a[7]) << 16) | f2bf(a[6]);
        *(uint4*)(S + (size_t)srow * 128 + li * 8) = o;
    }
}

extern "C" void kernel_launch(void* const* d_in, const int* in_sizes, int n_in,
                              void* d_out, int out_size, void* d_ws, size_t ws_size,
                              hipStream_t stream)
{
    const float* feat_user   = (const float*)d_in[0];
    const float* feat_item   = (const float*)d_in[1];
    const float* W_u2i       = (const float*)d_in[2];
    const float* b_u2i       = (const float*)d_in[3];
    const float* W_i2u       = (const float*)d_in[4];
    const float* b_i2u       = (const float*)d_in[5];
    const float* self_w_user = (const float*)d_in[6];
    const float* self_w_item = (const float*)d_in[7];
    const float* ln_g_user   = (const float*)d_in[8];
    const float* ln_b_user   = (const float*)d_in[9];
    const float* ln_g_item   = (const float*)d_in[10];
    const float* ln_b_item   = (const float*)d_in[11];
    const float* ffn_w1      = (const float*)d_in[12];
    const float* ffn_b1      = (const float*)d_in[13];
    const float* ffn_w2      = (const float*)d_in[14];
    const float* ffn_b2      = (const float*)d_in[15];
    const int* src_u2i       = (const int*)d_in[16];
    const int* dst_u2i       = (const int*)d_in[17];
    const int* src_i2u       = (const int*)d_in[18];
    const int* dst_i2u       = (const int*)d_in[19];

    const int NU = in_sizes[0] / 128;
    const int NI = in_sizes[1] / 128;
    const int E  = in_sizes[16];
    const int NR = NI + NU;                    // CSR rows, item-first
    const int NUp = (NU + 127) & ~127;
    const int NIp = (NI + 127) & ~127;
    const int NRp = NUp + NIp;                 // padded concat rows, user-first
    const int NBUK = (NR + BUK - 1) / BUK;

    // Workspace: S | fb | CSR arrays | transposed weights
    char* ws = (char*)d_ws;
    u16* S  = (u16*)ws;
    u16* fb = S + (size_t)NRp * 128;
    char* R2 = (char*)(fb + (size_t)NRp * 128);

    int* cnt    = (int*)R2;                     // NBUK+1
    int* crp    = cnt + (NBUK + 1);             // NBUK+1
    int* chead  = crp + (NBUK + 1);             // NBUK
    int* rowptr = chead + NBUK;                 // NR+1
    unsigned int* ebuf = (unsigned int*)(rowptr + NR + 1);   // 2E
    u16* eidx   = (u16*)(ebuf + 2 * (size_t)E);              // 2E
    u16* wts    = (u16*)(eidx + 2 * (size_t)E);
    u16* w_u2iT = wts;
    u16* w_i2uT = w_u2iT + 16384;
    u16* selfUT = w_i2uT + 16384;
    u16* selfIT = selfUT + 16384;
    u16* ffn1T  = selfIT + 16384;   // [256][128]
    u16* ffn2T  = ffn1T + 32768;    // [128][256]

    float* out = (float*)d_out;
    dim3 blk(256);
    const int nu4 = NU * 128 / 4, ni4 = NI * 128 / 4;
    const int padw = ((NUp - NU) + (NIp - NI)) * 32;
    const int prep_n = nu4 + ni4 + 131072 + 2 * padw + NBUK + 1;

    // 1. prep: casts + weight transposes + cnt zero + pad zero
    prep_k<<<dim3((prep_n + 255) / 256), blk, 0, stream>>>(
        feat_user, feat_item, fb, S, nu4, ni4, NU, NUp, NI, NIp,
        W_u2i, W_i2u, self_w_user, self_w_item, ffn_w1, ffn_w2,
        w_u2iT, w_i2uT, selfUT, selfIT, ffn1T, ffn2T, cnt, NBUK);

    // 2-5. CSR build (two-level counting sort by dst)
    chist_k<<<dim3(512), blk, 0, stream>>>(dst_u2i, dst_i2u, cnt, E, NI, NBUK);
    cscan_k<<<dim3(1), dim3(512), 0, stream>>>(cnt, crp, chead, rowptr, NBUK, NR);
    cpart_k<<<dim3(512), blk, 0, stream>>>(
        src_u2i, dst_u2i, src_i2u, dst_i2u, chead, ebuf, E, NI, NBUK);
    fsort_k<<<dim3(NBUK), blk, 0, stream>>>(crp, ebuf, rowptr, eidx, NR);

    // 6. gather raw-feature sums -> S (padded user-first)
    gather_k<<<dim3((NR + 3) / 4), blk, 0, stream>>>(
        rowptr, eidx, fb, S, NI, NR, NUp);

    // 7. msg GEMM + LN + ReLU + residual fused; h in-place over fb
    msgln_k<<<dim3(NRp / 128), blk, 0, stream>>>(
        S, fb, w_i2uT, selfUT, w_u2iT, selfIT,
        b_i2u, b_u2i, ln_g_user, ln_b_user, ln_g_item, ln_b_item, NUp);

    // 8. fused FFN: out = relu(h@W1+b1)@W2+b2 (hid lives in LDS)
    ffn_k<<<dim3(NRp / 128), blk, 0, stream>>>(
        fb, ffn1T, ffn_b1, ffn2T, ffn_b2, out, NU, NUp, NI);
}

// Round 9
// 301.581 us; speedup vs baseline: 1.1316x; 1.1316x over previous
//
#include <hip/hip_runtime.h>

typedef unsigned short u16;
typedef __attribute__((ext_vector_type(4))) float f32x4;
typedef __attribute__((ext_vector_type(8))) short bf16x8;

#define MAXB 512      // max coarse buckets one scan block supports
#define BUK  256      // dst rows per coarse bucket
#define EMAX 4096     // max edges per bucket (mean 3072, ~18 sigma headroom)

__device__ __forceinline__ float bf2f(u16 u) {
    union { unsigned int i; float f; } v; v.i = ((unsigned int)u) << 16; return v.f;
}
__device__ __forceinline__ u16 f2bf(float f) {
    union { float f; unsigned int i; } v; v.f = f;
    unsigned int r = v.i + 0x7fffu + ((v.i >> 16) & 1u);
    return (u16)(r >> 16);
}
__device__ __forceinline__ void gload16(const void* g, void* l) {
    __builtin_amdgcn_global_load_lds(
        (const __attribute__((address_space(1))) unsigned int*)g,
        (__attribute__((address_space(3))) unsigned int*)l, 16, 0, 0);
}

// 256 thr = 4 waves, 128x128 C tile, wave = 64x64 (4x4 of 16x16x32 bf16 MFMA)
// LDS tiles are stored with a 16B-granule XOR swizzle: granule g of row r
// lives at physical granule g ^ (r&7). DMA staging swizzles the global
// SOURCE column (LDS dest must stay linear-in-lane); all reads apply the
// same XOR -> 16-lane fragment reads become 2-way (free) instead of 16-way.
#define MFMA_VARS \
    const int tid = threadIdx.x, w = tid >> 6, l = tid & 63; \
    const int wr = (w >> 1) * 64, wc = (w & 1) * 64; \
    const int quad = l >> 4, lan = l & 15; (void)tid;

#define ACC_INIT(A) \
    _Pragma("unroll") for (int i = 0; i < 4; i++) \
    _Pragma("unroll") for (int j = 0; j < 4; j++) A[i][j] = (f32x4){0.f,0.f,0.f,0.f};

#define STAGE_AW(Aptr, sA, Wptr, sW) \
    _Pragma("unroll") for (int it = 0; it < 8; it++) { \
        int o = ((it * 4 + w) * 64 + l) * 16; \
        int row = o >> 8; \
        int sg = ((o >> 4) & 15) ^ (row & 7); \
        gload16((Aptr) + (size_t)row * (sA) + sg * 8, (char*)As + o); \
        gload16((Wptr) + (size_t)row * (sW) + sg * 8, (char*)Ws + o); \
    }

#define STAGE_W(Wptr, sW) \
    _Pragma("unroll") for (int it = 0; it < 8; it++) { \
        int o = ((it * 4 + w) * 64 + l) * 16; \
        int row = o >> 8; \
        int sg = ((o >> 4) & 15) ^ (row & 7); \
        gload16((Wptr) + (size_t)row * (sW) + sg * 8, (char*)Ws + o); \
    }

#define COMPUTE(A) \
    _Pragma("unroll") for (int kk = 0; kk < 4; kk++) { \
        bf16x8 af[4], bfr[4]; \
        _Pragma("unroll") for (int i = 0; i < 4; i++) { \
            int ra = wr + i * 16 + lan; \
            af[i] = *(const bf16x8*)&As[ra * 128 + (((kk * 4 + quad) ^ (ra & 7)) << 3)]; } \
        _Pragma("unroll") for (int j = 0; j < 4; j++) { \
            int rb = wc + j * 16 + lan; \
            bfr[j] = *(const bf16x8*)&Ws[rb * 128 + (((kk * 4 + quad) ^ (rb & 7)) << 3)]; } \
        _Pragma("unroll") for (int i = 0; i < 4; i++) \
        _Pragma("unroll") for (int j = 0; j < 4; j++) \
            A[i][j] = __builtin_amdgcn_mfma_f32_16x16x32_bf16(af[i], bfr[j], A[i][j], 0,0,0); \
    }

// ---------------------------------------------------------------------------
// msgln: x = S @ Wrel^T + fb @ Wself^T + bm; h = relu(LN(x)*g + b) + fb.
// LN stats in-register (shfl over 16-lane groups) + 2KB LDS half-exchange.
// Residual fb read back from LDS As (still staged, swizzled). In-place to fb.
// ---------------------------------------------------------------------------
__global__ __launch_bounds__(256) void msgln_k(
    const u16* __restrict__ S, u16* __restrict__ fb,
    const u16* __restrict__ wUrel, const u16* __restrict__ wUself,
    const u16* __restrict__ wIrel, const u16* __restrict__ wIself,
    const float* __restrict__ bmU, const float* __restrict__ bmI,
    const float* __restrict__ gU, const float* __restrict__ bU,
    const float* __restrict__ gI, const float* __restrict__ bI,
    int NUp)
{
    __shared__ __align__(16) u16 As[128 * 128];
    __shared__ __align__(16) u16 Ws[128 * 128];
    __shared__ float ps[128][2][2];
    MFMA_VARS
    const int m0 = blockIdx.x * 128;
    const bool isU = m0 < NUp;
    const u16* W0 = isU ? wUrel : wIrel;
    const u16* W1 = isU ? wUself : wIself;
    const float* bm = isU ? bmU : bmI;
    const float* g  = isU ? gU : gI;
    const float* b  = isU ? bU : bI;

    f32x4 acc[4][4];
    ACC_INIT(acc)

    STAGE_AW(S + (size_t)m0 * 128, 128, W0, 128)
    __syncthreads();
    COMPUTE(acc)
    __syncthreads();
    STAGE_AW(fb + (size_t)m0 * 128, 128, W1, 128)
    __syncthreads();
    COMPUTE(acc)

    const int half = wc >> 6;
    float bm4[4], g4[4], b4[4];
#pragma unroll
    for (int j = 0; j < 4; j++) {
        int col = wc + j * 16 + lan;
        bm4[j] = bm[col]; g4[j] = g[col]; b4[j] = b[col];
    }
#pragma unroll
    for (int i = 0; i < 4; i++) {
#pragma unroll
        for (int r = 0; r < 4; r++) {
            float s = 0.f, q = 0.f;
#pragma unroll
            for (int j = 0; j < 4; j++) {
                float v = acc[i][j][r] + bm4[j];
                s += v; q += v * v;
            }
#pragma unroll
            for (int o = 1; o < 16; o <<= 1) {
                s += __shfl_xor(s, o, 64);
                q += __shfl_xor(q, o, 64);
            }
            if (lan == 0) {
                int rl = wr + i * 16 + quad * 4 + r;
                ps[rl][half][0] = s;
                ps[rl][half][1] = q;
            }
        }
    }
    __syncthreads();
#pragma unroll
    for (int i = 0; i < 4; i++) {
#pragma unroll
        for (int r = 0; r < 4; r++) {
            int rl = wr + i * 16 + quad * 4 + r;
            float sum = ps[rl][0][0] + ps[rl][1][0];
            float sq  = ps[rl][0][1] + ps[rl][1][1];
            float mean = sum * 0.0078125f;
            float var  = sq * 0.0078125f - mean * mean;
            float inv  = rsqrtf(var + 1e-5f);
#pragma unroll
            for (int j = 0; j < 4; j++) {
                int col = wc + j * 16 + lan;
                int sgc = ((col >> 3) ^ (rl & 7)) << 3;      // swizzled residual read
                float v = acc[i][j][r] + bm4[j];
                float y = fmaxf(fmaf((v - mean) * inv, g4[j], b4[j]), 0.f)
                          + bf2f(As[rl * 128 + sgc + (col & 7)]);
                fb[(size_t)(m0 + rl) * 128 + col] = f2bf(y);
            }
        }
    }
}

// ---------------------------------------------------------------------------
// Fused FFN: out = relu(h @ W1T^T + b1) @ W2T^T + b2.
// Phase 1: hid[128][256] in regs (two W1 col-halves); store to 64KB LDS with
// XOR swizzle. Phase 2: K=256 MFMA, A from swizzled LDS (2-way, free),
// W2T B-fragments streamed from global (64KB, L2-resident).
// fp32 out with pad-skip row remap.
// ---------------------------------------------------------------------------
__global__ __launch_bounds__(256) void ffn_k(
    const u16* __restrict__ h, const u16* __restrict__ W1T,
    const float* __restrict__ b1, const u16* __restrict__ W2T,
    const float* __restrict__ b2, float* __restrict__ out,
    int NU, int NUp, int NI)
{
    __shared__ __align__(16) u16 lds[2 * 128 * 128];
    u16* As = lds;
    u16* Ws = lds + 16384;
    MFMA_VARS
    const int m0 = blockIdx.x * 128;

    f32x4 acc1[4][4], acc2[4][4];
    ACC_INIT(acc1)
    ACC_INIT(acc2)

    STAGE_AW(h + (size_t)m0 * 128, 128, W1T, 128)
    __syncthreads();
    COMPUTE(acc1)
    __syncthreads();
    STAGE_W(W1T + (size_t)128 * 128, 128)
    __syncthreads();
    COMPUTE(acc2)
    __syncthreads();   // all waves done reading As/Ws

    // hid -> LDS as [row][256] bf16, granule-swizzled (relu + b1)
    float b1a[4], b1b[4];
#pragma unroll
    for (int j = 0; j < 4; j++) {
        b1a[j] = b1[wc + j * 16 + lan];
        b1b[j] = b1[128 + wc + j * 16 + lan];
    }
    u16* H = lds;
#pragma unroll
    for (int i = 0; i < 4; i++) {
#pragma unroll
        for (int r = 0; r < 4; r++) {
            int rl = wr + i * 16 + quad * 4 + r;
#pragma unroll
            for (int j = 0; j < 4; j++) {
                int col = wc + j * 16 + lan;
                int gA = col >> 3, od = col & 7;
                H[rl * 256 + ((gA ^ (rl & 7)) << 3) + od] =
                    f2bf(fmaxf(acc1[i][j][r] + b1a[j], 0.f));
                H[rl * 256 + (((16 + gA) ^ (rl & 7)) << 3) + od] =
                    f2bf(fmaxf(acc2[i][j][r] + b1b[j], 0.f));
            }
        }
    }
    __syncthreads();

    // phase 2: out-tile = H @ W2T^T  (K = 256)
    f32x4 acc3[4][4];
    ACC_INIT(acc3)
#pragma unroll
    for (int kk = 0; kk < 8; kk++) {
        bf16x8 af[4], bfr[4];
#pragma unroll
        for (int i = 0; i < 4; i++) {
            int ra = wr + i * 16 + lan;
            int lg = kk * 4 + quad;
            af[i] = *(const bf16x8*)&H[ra * 256 + ((lg ^ (ra & 7)) << 3)];
        }
#pragma unroll
        for (int j = 0; j < 4; j++)
            bfr[j] = *(const bf16x8*)&W2T[(size_t)(wc + j * 16 + lan) * 256 + kk * 32 + quad * 8];
#pragma unroll
        for (int i = 0; i < 4; i++)
#pragma unroll
            for (int j = 0; j < 4; j++)
                acc3[i][j] = __builtin_amdgcn_mfma_f32_16x16x32_bf16(af[i], bfr[j], acc3[i][j], 0, 0, 0);
    }

#pragma unroll
    for (int j = 0; j < 4; j++) {
        int col = wc + j * 16 + lan;
        float bb = b2[col];
#pragma unroll
        for (int i = 0; i < 4; i++) {
            int row0 = m0 + wr + i * 16 + quad * 4;
#pragma unroll
            for (int r = 0; r < 4; r++) {
                int gr = row0 + r, orow;
                if (gr < NUp) { if (gr >= NU) continue; orow = gr; }
                else { int ir = gr - NUp; if (ir >= NI) continue; orow = NU + ir; }
                out[(size_t)orow * 128 + col] = acc3[i][j][r] + bb;
            }
        }
    }
}

// ---------------------------------------------------------------------------
// prep: feature casts (user-first padded layout) + 6 weight transposes +
// cnt zeroing + pad-row zeroing of S and fb.
// ---------------------------------------------------------------------------
__global__ __launch_bounds__(256) void prep_k(
    const float* __restrict__ fu, const float* __restrict__ fi,
    u16* __restrict__ fb, u16* __restrict__ S,
    int nu4, int ni4, int NU, int NUp, int NI, int NIp,
    const float* __restrict__ w0, const float* __restrict__ w1,
    const float* __restrict__ w2, const float* __restrict__ w3,
    const float* __restrict__ w4, const float* __restrict__ w5,
    u16* __restrict__ o0, u16* __restrict__ o1, u16* __restrict__ o2,
    u16* __restrict__ o3, u16* __restrict__ o4, u16* __restrict__ o5,
    int* __restrict__ cnt, int NBUK)
{
    int t = blockIdx.x * 256 + threadIdx.x;
    int nc = nu4 + ni4;
    if (t < nc) {
        const float* X; u16* Y; int idx;
        if (t < nu4) { X = fu; Y = fb; idx = t; }
        else { X = fi; Y = fb + (size_t)NUp * 128; idx = t - nu4; }
        float4 v = ((const float4*)X)[idx];
        ((ushort4*)Y)[idx] = make_ushort4(f2bf(v.x), f2bf(v.y), f2bf(v.z), f2bf(v.w));
        return;
    }
    int u = t - nc;
    if (u < 131072) {
        const float* W; u16* O; int K, N, idx;
        if (u < 65536) {
            int s = u >> 14; idx = u & 16383; K = 128; N = 128;
            W = s == 0 ? w0 : s == 1 ? w1 : s == 2 ? w2 : w3;
            O = s == 0 ? o0 : s == 1 ? o1 : s == 2 ? o2 : o3;
        } else {
            int v2 = u - 65536; int s = v2 >> 15; idx = v2 & 32767;
            if (s == 0) { W = w4; O = o4; K = 128; N = 256; }
            else        { W = w5; O = o5; K = 256; N = 128; }
        }
        int k = idx / N, n = idx % N;
        O[n * K + k] = f2bf(W[idx]);
        return;
    }
    int u2 = u - 131072;
    int padrows = (NUp - NU) + (NIp - NI);
    int padw = padrows * 32;           // ushort4 per array
    if (u2 < 2 * padw) {
        int arr = u2 / padw, k = u2 % padw;
        int prow = k >> 5, c4 = k & 31;
        int row = (prow < NUp - NU) ? (NU + prow) : (NUp + NI + (prow - (NUp - NU)));
        u16* B = arr ? fb : S;
        ((ushort4*)B)[(size_t)row * 32 + c4] = make_ushort4(0, 0, 0, 0);
        return;
    }
    int c = u2 - 2 * padw;
    if (c <= NBUK) cnt[c] = 0;
}

// ---------------------------------------------------------------------------
// CSR build: coarse histogram -> scan -> partition -> per-bucket LDS sort.
// CSR row space item-first: [0,NI)=item dst, [NI,NR)=user dst.
// ---------------------------------------------------------------------------
__global__ __launch_bounds__(256) void chist_k(
    const int* __restrict__ dst0, const int* __restrict__ dst1,
    int* __restrict__ cnt, int E, int NI, int NBUK)
{
    __shared__ int lh[MAXB];
    int t = threadIdx.x;
    for (int i = t; i < MAXB; i += 256) lh[i] = 0;
    __syncthreads();
    for (long long e = (long long)blockIdx.x * 256 + t; e < 2LL * E;
         e += (long long)gridDim.x * 256) {
        int row = (e < E) ? dst0[e] : NI + dst1[e - E];
        atomicAdd(&lh[row >> 8], 1);
    }
    __syncthreads();
    for (int i = t; i < NBUK; i += 256)
        if (lh[i]) atomicAdd(&cnt[i], lh[i]);
}

__global__ __launch_bounds__(512) void cscan_k(
    const int* __restrict__ cnt, int* __restrict__ crp, int* __restrict__ chead,
    int* __restrict__ rowptr, int NBUK, int NR)
{
    __shared__ int s[512];
    int t = threadIdx.x;
    int carry = 0;
    for (int base = 0; base < NBUK; base += 512) {
        int i = base + t;
        int v = (i < NBUK) ? cnt[i] : 0;
        s[t] = v;
        __syncthreads();
        for (int off = 1; off < 512; off <<= 1) {
            int x = (t >= off) ? s[t - off] : 0;
            __syncthreads();
            s[t] += x;
            __syncthreads();
        }
        int excl = s[t] - v + carry;
        if (i < NBUK) { crp[i] = excl; chead[i] = excl; }
        carry += s[511];
        __syncthreads();
    }
    if (t == 0) { crp[NBUK] = carry; rowptr[NR] = carry; }
}

__global__ __launch_bounds__(256) void cpart_k(
    const int* __restrict__ src0, const int* __restrict__ dst0,
    const int* __restrict__ src1, const int* __restrict__ dst1,
    int* __restrict__ chead, unsigned int* __restrict__ ebuf,
    int E, int NI, int NBUK)
{
    __shared__ int lh[MAXB], lb[MAXB], lo[MAXB];
    int t = threadIdx.x;
    long long total = 2LL * E;
    long long per = (total + gridDim.x - 1) / gridDim.x;
    long long r0 = (long long)blockIdx.x * per;
    long long r1 = r0 + per; if (r1 > total) r1 = total;

    for (int i = t; i < MAXB; i += 256) { lh[i] = 0; lo[i] = 0; }
    __syncthreads();
    for (long long e = r0 + t; e < r1; e += 256) {
        int row = (e < E) ? dst0[e] : NI + dst1[e - E];
        atomicAdd(&lh[row >> 8], 1);
    }
    __syncthreads();
    for (int i = t; i < NBUK; i += 256)
        if (lh[i]) lb[i] = atomicAdd(&chead[i], lh[i]);
    __syncthreads();
    for (long long e = r0 + t; e < r1; e += 256) {
        int row, src;
        if (e < E) { row = dst0[e]; src = src0[e]; }
        else       { row = NI + dst1[e - E]; src = src1[e - E]; }
        int bin = row >> 8;
        int off = atomicAdd(&lo[bin], 1);
        ebuf[lb[bin] + off] = ((unsigned int)(row & 255) << 16) | (unsigned int)src;
    }
}

__global__ __launch_bounds__(256) void fsort_k(
    const int* __restrict__ crp, const unsigned int* __restrict__ ebuf,
    int* __restrict__ rowptr, u16* __restrict__ eidx, int NR)
{
    __shared__ unsigned int ep[EMAX];
    __shared__ u16 ss[EMAX];
    __shared__ int h[BUK], hd[BUK];
    int b = blockIdx.x, t = threadIdx.x;
    int base = crp[b];
    int n = crp[b + 1] - base;
    if (n > EMAX) n = EMAX;

    for (int i = t; i < n; i += 256) ep[i] = ebuf[base + i];
    if (t < BUK) h[t] = 0;
    __syncthreads();
    for (int i = t; i < n; i += 256) atomicAdd(&h[ep[i] >> 16], 1);
    __syncthreads();
    int v = (t < BUK) ? h[t] : 0;
    for (int off = 1; off < 256; off <<= 1) {
        int x = (t >= off) ? h[t - off] : 0;
        __syncthreads();
        if (t < BUK) h[t] += x;
        __syncthreads();
    }
    int excl = (t < BUK) ? (h[t] - v) : 0;
    if (t < BUK) {
        int absrow = b * BUK + t;
        if (absrow < NR) rowptr[absrow] = base + excl;
        hd[t] = excl;
    }
    __syncthreads();
    for (int i = t; i < n; i += 256) {
        unsigned int p = ep[i];
        int pos = atomicAdd(&hd[p >> 16], 1);
        ss[pos] = (u16)(p & 0xffffu);
    }
    __syncthreads();
    for (int i = t; i < n; i += 256) eidx[base + i] = ss[i];
}

// ---------------------------------------------------------------------------
// Gather: wave per csr row, 16 edges in flight (4 clamped uint4 loads,
// predicated accumulate), fp32 acc, shfl-reduce, bf16 out (padded layout).
// ---------------------------------------------------------------------------
__global__ __launch_bounds__(256) void gather_k(
    const int* __restrict__ rowptr, const u16* __restrict__ eidx,
    const u16* __restrict__ fb, u16* __restrict__ S,
    int NI, int NR, int NUp)
{
    int row = blockIdx.x * 4 + (threadIdx.x >> 6);
    int l = threadIdx.x & 63;
    if (row >= NR) return;
    const u16* F = (row < NI) ? fb : fb + (size_t)NUp * 128;
    int srow = (row < NI) ? (NUp + row) : (row - NI);
    int start = rowptr[row], end = rowptr[row + 1];
    int sub = l >> 4, li = l & 15;

    float a[8];
#pragma unroll
    for (int k = 0; k < 8; k++) a[k] = 0.f;

    for (int j = start; j < end; j += 16) {
        int idx[4]; uint4 v[4];
#pragma unroll
        for (int u = 0; u < 4; u++) {
            int je = j + u * 4 + sub;
            int c = je < end ? je : end - 1;
            idx[u] = eidx[c];
        }
#pragma unroll
        for (int u = 0; u < 4; u++)
            v[u] = *(const uint4*)(F + (size_t)idx[u] * 128 + li * 8);
#pragma unroll
        for (int u = 0; u < 4; u++) {
            if (j + u * 4 + sub < end) {
                unsigned int ww[4] = {v[u].x, v[u].y, v[u].z, v[u].w};
#pragma unroll
                for (int p = 0; p < 4; p++) {
                    a[2*p]   += bf2f((u16)(ww[p] & 0xffffu));
                    a[2*p+1] += bf2f((u16)(ww[p] >> 16));
                }
            }
        }
    }
#pragma unroll
    for (int k = 0; k < 8; k++) {
        a[k] += __shfl_xor(a[k], 16, 64);
        a[k] += __shfl_xor(a[k], 32, 64);
    }
    if (sub == 0) {
        uint4 o;
        o.x = ((unsigned int)f2bf(a[1]) << 16) | f2bf(a[0]);
        o.y = ((unsigned int)f2bf(a[3]) << 16) | f2bf(a[2]);
        o.z = ((unsigned int)f2bf(a[5]) << 16) | f2bf(a[4]);
        o.w = ((unsigned int)f2bf(a[7]) << 16) | f2bf(a[6]);
        *(uint4*)(S + (size_t)srow * 128 + li * 8) = o;
    }
}

extern "C" void kernel_launch(void* const* d_in, const int* in_sizes, int n_in,
                              void* d_out, int out_size, void* d_ws, size_t ws_size,
                              hipStream_t stream)
{
    const float* feat_user   = (const float*)d_in[0];
    const float* feat_item   = (const float*)d_in[1];
    const float* W_u2i       = (const float*)d_in[2];
    const float* b_u2i       = (const float*)d_in[3];
    const float* W_i2u       = (const float*)d_in[4];
    const float* b_i2u       = (const float*)d_in[5];
    const float* self_w_user = (const float*)d_in[6];
    const float* self_w_item = (const float*)d_in[7];
    const float* ln_g_user   = (const float*)d_in[8];
    const float* ln_b_user   = (const float*)d_in[9];
    const float* ln_g_item   = (const float*)d_in[10];
    const float* ln_b_item   = (const float*)d_in[11];
    const float* ffn_w1      = (const float*)d_in[12];
    const float* ffn_b1      = (const float*)d_in[13];
    const float* ffn_w2      = (const float*)d_in[14];
    const float* ffn_b2      = (const float*)d_in[15];
    const int* src_u2i       = (const int*)d_in[16];
    const int* dst_u2i       = (const int*)d_in[17];
    const int* src_i2u       = (const int*)d_in[18];
    const int* dst_i2u       = (const int*)d_in[19];

    const int NU = in_sizes[0] / 128;
    const int NI = in_sizes[1] / 128;
    const int E  = in_sizes[16];
    const int NR = NI + NU;                    // CSR rows, item-first
    const int NUp = (NU + 127) & ~127;
    const int NIp = (NI + 127) & ~127;
    const int NRp = NUp + NIp;                 // padded concat rows, user-first
    const int NBUK = (NR + BUK - 1) / BUK;

    // Workspace: S | fb | CSR arrays | transposed weights
    char* ws = (char*)d_ws;
    u16* S  = (u16*)ws;
    u16* fb = S + (size_t)NRp * 128;
    char* R2 = (char*)(fb + (size_t)NRp * 128);

    int* cnt    = (int*)R2;                     // NBUK+1
    int* crp    = cnt + (NBUK + 1);             // NBUK+1
    int* chead  = crp + (NBUK + 1);             // NBUK
    int* rowptr = chead + NBUK;                 // NR+1
    unsigned int* ebuf = (unsigned int*)(rowptr + NR + 1);   // 2E
    u16* eidx   = (u16*)(ebuf + 2 * (size_t)E);              // 2E
    u16* wts    = (u16*)(eidx + 2 * (size_t)E);
    u16* w_u2iT = wts;
    u16* w_i2uT = w_u2iT + 16384;
    u16* selfUT = w_i2uT + 16384;
    u16* selfIT = selfUT + 16384;
    u16* ffn1T  = selfIT + 16384;   // [256][128]
    u16* ffn2T  = ffn1T + 32768;    // [128][256]

    float* out = (float*)d_out;
    dim3 blk(256);
    const int nu4 = NU * 128 / 4, ni4 = NI * 128 / 4;
    const int padw = ((NUp - NU) + (NIp - NI)) * 32;
    const int prep_n = nu4 + ni4 + 131072 + 2 * padw + NBUK + 1;

    // 1. prep: casts + weight transposes + cnt zero + pad zero
    prep_k<<<dim3((prep_n + 255) / 256), blk, 0, stream>>>(
        feat_user, feat_item, fb, S, nu4, ni4, NU, NUp, NI, NIp,
        W_u2i, W_i2u, self_w_user, self_w_item, ffn_w1, ffn_w2,
        w_u2iT, w_i2uT, selfUT, selfIT, ffn1T, ffn2T, cnt, NBUK);

    // 2-5. CSR build (two-level counting sort by dst)
    chist_k<<<dim3(512), blk, 0, stream>>>(dst_u2i, dst_i2u, cnt, E, NI, NBUK);
    cscan_k<<<dim3(1), dim3(512), 0, stream>>>(cnt, crp, chead, rowptr, NBUK, NR);
    cpart_k<<<dim3(512), blk, 0, stream>>>(
        src_u2i, dst_u2i, src_i2u, dst_i2u, chead, ebuf, E, NI, NBUK);
    fsort_k<<<dim3(NBUK), blk, 0, stream>>>(crp, ebuf, rowptr, eidx, NR);

    // 6. gather raw-feature sums -> S (padded user-first)
    gather_k<<<dim3((NR + 3) / 4), blk, 0, stream>>>(
        rowptr, eidx, fb, S, NI, NR, NUp);

    // 7. msg GEMM + LN + ReLU + residual fused; h in-place over fb
    msgln_k<<<dim3(NRp / 128), blk, 0, stream>>>(
        S, fb, w_i2uT, selfUT, w_u2iT, selfIT,
        b_i2u, b_u2i, ln_g_user, ln_b_user, ln_g_item, ln_b_item, NUp);

    // 8. fused FFN: out = relu(h@W1+b1)@W2+b2 (hid swizzled in LDS)
    ffn_k<<<dim3(NRp / 128), blk, 0, stream>>>(
        fb, ffn1T, ffn_b1, ffn2T, ffn_b2, out, NU, NUp, NI);
}